// Round 9
// baseline (134.839 us; speedup 1.0000x reference)
//
#include <hip/hip_runtime.h>
#include <stdint.h>

// Problem constants (match reference)
#define B_ 4096
#define C_ 200
#define P_ 32
#define F_ 512
#define N_ (C_*P_)        // 6400 prototypes total
#define ALPHA_ 5.0
#define EPS_ 1e-8
#define NROWS_ (B_ + N_)  // 10496 sumsq rows (x2 then p2)

typedef unsigned char u8;
typedef unsigned int u32;
typedef __attribute__((ext_vector_type(4))) float floatx4;  // MFMA C/D frag

union frag16 { int4 v; long l[2]; };   // 16 fp8 = two MFMA k-slices (virtual-K)

// monotone float<->uint order encoding (for atomicMin on float values)
__device__ __forceinline__ u32 fenc(float f) {
    u32 u = __float_as_uint(f);
    return (u & 0x80000000u) ? ~u : (u | 0x80000000u);
}
__device__ __forceinline__ float fdec(u32 e) {
    u32 u = (e & 0x80000000u) ? (e ^ 0x80000000u) : ~e;
    return __uint_as_float(u);
}

// init: sumsq = 0 (10496), swe = 0xFFFFFFFF (4096). 57*256 = 14592 threads.
__global__ void init_kernel(float* __restrict__ sumsq, u32* __restrict__ swe) {
    int i = blockIdx.x * 256 + threadIdx.x;
    if (i < NROWS_) sumsq[i] = 0.f;
    else if (i < NROWS_ + B_) swe[i - NROWS_] = 0xFFFFFFFFu;
}

// ---------- prep: fp32 -> fp8 e4m3 packed + row sum-of-squares (x2 | p2) ----------
// Packed layout: o = tm*512 + kc*64 + q*16 + r (16-B units); byte (tm*8+kc)*1024 +
// (q*16+r)*16 holds features [kc*64+q*16,+16) of row tm*16+r. Output-indexed: writes
// wave-contiguous 1KB, reads per-lane 64B-aligned. One wave = one (tm,kc); lanes with
// equal r (q=0..3 at lane r+16q) reduce to a row-chunk sumsq, atomically accumulated.
__global__ void prep_kernel(const float* __restrict__ outputs, const float* __restrict__ clusters,
                            u8* __restrict__ At, u8* __restrict__ Bt, float* __restrict__ sumsq) {
    int t = blockIdx.x * 256 + threadIdx.x;
    const float* src; u8* dst; int o, rbase;
    if (t < B_ * 32) { o = t;           src = outputs;  dst = At; rbase = 0; }
    else             { o = t - B_ * 32; src = clusters; dst = Bt; rbase = B_; }
    const int tm = o >> 9, kc = (o >> 6) & 7, q = (o >> 4) & 3, r = o & 15;
    const int row = tm * 16 + r;
    const float4* s = (const float4*)(src + (size_t)row * F_ + kc * 64 + q * 16);
    float4 v0 = s[0], v1 = s[1], v2 = s[2], v3 = s[3];
    int4 w;
    w.x = __builtin_amdgcn_cvt_pk_fp8_f32(v0.x, v0.y, 0, false);
    w.x = __builtin_amdgcn_cvt_pk_fp8_f32(v0.z, v0.w, w.x, true);
    w.y = __builtin_amdgcn_cvt_pk_fp8_f32(v1.x, v1.y, 0, false);
    w.y = __builtin_amdgcn_cvt_pk_fp8_f32(v1.z, v1.w, w.y, true);
    w.z = __builtin_amdgcn_cvt_pk_fp8_f32(v2.x, v2.y, 0, false);
    w.z = __builtin_amdgcn_cvt_pk_fp8_f32(v2.z, v2.w, w.z, true);
    w.w = __builtin_amdgcn_cvt_pk_fp8_f32(v3.x, v3.y, 0, false);
    w.w = __builtin_amdgcn_cvt_pk_fp8_f32(v3.z, v3.w, w.w, true);
    *(int4*)(dst + (size_t)o * 16) = w;

    float ss = v0.x*v0.x + v0.y*v0.y + v0.z*v0.z + v0.w*v0.w
             + v1.x*v1.x + v1.y*v1.y + v1.z*v1.z + v1.w*v1.w
             + v2.x*v2.x + v2.y*v2.y + v2.z*v2.z + v2.w*v2.w
             + v3.x*v3.x + v3.y*v3.y + v3.z*v3.z + v3.w*v3.w;
    ss += __shfl_xor(ss, 16);
    ss += __shfl_xor(ss, 32);
    if ((o & 63) < 16) atomicAdd(&sumsq[rbase + row], ss);   // 16 lanes, 16 consecutive rows
}

// ---------- score kernel: fp8 MFMA GEMM + FULLY fused selection ----------
// R6 K-loop (proven): LDS double-buffer, 1-stage-ahead prefetch, one barrier/stage.
// Epilogue: each (b,class) min is computed by exactly ONE (block,wave,ch) lane-group, so
// selection fuses here: target class -> unique plain store stw[b]; other classes ->
// atomicMin(swe[b], enc(v)). min_d buffer and select_kernel eliminated.
#define BM 128
#define BN 128

typedef const __attribute__((address_space(1))) unsigned int gu32_t;
typedef __attribute__((address_space(3))) unsigned int lu32_t;

__device__ __forceinline__ void gld16(const u8* g, u8* l) {
    __builtin_amdgcn_global_load_lds((gu32_t*)g, (lu32_t*)l, 16, 0, 0);
}

__global__ __launch_bounds__(256, 4)
void score_kernel(const u8* __restrict__ At, const u8* __restrict__ Bt,
                  const float* __restrict__ p2, const int* __restrict__ tgt,
                  float* __restrict__ stw, u32* __restrict__ swe) {
    __shared__ __align__(16) u8 lds[2][16384];   // [buf][ A: 8 tiles x 1KB | B: 8 tiles x 1KB ]

    const int tid  = threadIdx.x;
    const int lane = tid & 63;
    const int w    = tid >> 6;          // wave 0..3 (2x2 wave grid, 64x64 per wave)
    const int wm   = w >> 1, wn = w & 1;
    const int bx   = blockIdx.x;        // n-tile 0..49
    const int by   = blockIdx.y;        // m-tile 0..31
    const int m0   = by * BM, n0 = bx * BN;
    const int mrow = lane & 15;
    const int quad = lane >> 4;
    const int l16  = lane * 16;

    const u8* ag = At + ((size_t)(by * 8) << 13);   // 8 row-tiles x 8KB each
    const u8* bg = Bt + ((size_t)(bx * 8) << 13);

    floatx4 zf = {0.f, 0.f, 0.f, 0.f};
    floatx4 acc[4][4];
#pragma unroll
    for (int i = 0; i < 4; ++i)
#pragma unroll
        for (int j = 0; j < 4; ++j) acc[i][j] = zf;

    // prologue: prefetch stage 0 into buf 0 (wave w loads A tiles {w,w+4}, B tiles {w,w+4})
    gld16(ag + ((w * 8) << 10) + l16,           lds[0] + w * 1024);
    gld16(ag + (((w + 4) * 8) << 10) + l16,     lds[0] + (w + 4) * 1024);
    gld16(bg + ((w * 8) << 10) + l16,           lds[0] + 8192 + w * 1024);
    gld16(bg + (((w + 4) * 8) << 10) + l16,     lds[0] + 8192 + (w + 4) * 1024);
    __syncthreads();

#pragma unroll
    for (int kc = 0; kc < 8; ++kc) {
        const int cur = kc & 1;
        if (kc < 7) {
            const int nb = cur ^ 1, kn = kc + 1;
            gld16(ag + ((w * 8 + kn) << 10) + l16,         lds[nb] + w * 1024);
            gld16(ag + (((w + 4) * 8 + kn) << 10) + l16,   lds[nb] + (w + 4) * 1024);
            gld16(bg + ((w * 8 + kn) << 10) + l16,         lds[nb] + 8192 + w * 1024);
            gld16(bg + (((w + 4) * 8 + kn) << 10) + l16,   lds[nb] + 8192 + (w + 4) * 1024);
        }
        frag16 a[4], b[4];
#pragma unroll
        for (int t = 0; t < 4; ++t) {
            a[t].v = *(const int4*)(lds[cur] + (wm * 4 + t) * 1024 + l16);
            b[t].v = *(const int4*)(lds[cur] + 8192 + (wn * 4 + t) * 1024 + l16);
        }
#pragma unroll
        for (int s = 0; s < 2; ++s)
#pragma unroll
            for (int mt = 0; mt < 4; ++mt)
#pragma unroll
                for (int nt = 0; nt < 4; ++nt)
                    acc[mt][nt] = __builtin_amdgcn_mfma_f32_16x16x32_fp8_fp8(
                        a[mt].l[s], b[nt].l[s], acc[mt][nt], 0, 0, 0);
        __syncthreads();
    }

    // Epilogue: score = p2[n] - 2*xp (x2 added in finalize). C/D layout: col = lane&15,
    // row = quad*4 + reg. Per (b,cls): min over 32 protos (2 halves + 16-lane butterfly).
    float pg[4];
#pragma unroll
    for (int nt = 0; nt < 4; ++nt) pg[nt] = p2[n0 + wn * 64 + nt * 16 + mrow];

#pragma unroll
    for (int ch = 0; ch < 2; ++ch) {
        const int cls = bx * 4 + wn * 2 + ch;
#pragma unroll
        for (int mt = 0; mt < 4; ++mt)
#pragma unroll
            for (int reg = 0; reg < 4; ++reg) {
                float v = fminf(pg[ch * 2]     - 2.0f * acc[mt][ch * 2][reg],
                                pg[ch * 2 + 1] - 2.0f * acc[mt][ch * 2 + 1][reg]);
#pragma unroll
                for (int m = 8; m >= 1; m >>= 1) v = fminf(v, __shfl_xor(v, m));
                if (mrow == 0) {
                    int grow = m0 + wm * 64 + mt * 16 + quad * 4 + reg;
                    if (tgt[grow] == cls) stw[grow] = v;          // unique writer
                    else atomicMin(&swe[grow], fenc(v));          // 199 per address
                }
            }
    }
}

// Final: per-sample losses from stw/swe/x2, block-reduce, loss
__global__ __launch_bounds__(1024)
void finalize_kernel(const float* __restrict__ stw, const u32* __restrict__ swe,
                     const float* __restrict__ x2, float* __restrict__ out) {
    __shared__ float r1[16], r2[16];
    int tid = threadIdx.x;
    float s1 = 0.f, s2 = 0.f;
#pragma unroll
    for (int i = 0; i < 4; ++i) {
        int b = tid + i * 1024;
        float xx = x2[b];
        s1 += xx + stw[b];
        s2 += xx + fdec(swe[b]);
    }
#pragma unroll
    for (int m = 32; m >= 1; m >>= 1) { s1 += __shfl_xor(s1, m); s2 += __shfl_xor(s2, m); }
    if ((tid & 63) == 0) { r1[tid >> 6] = s1; r2[tid >> 6] = s2; }
    __syncthreads();
    if (tid == 0) {
        double t1 = 0.0, t2 = 0.0;
#pragma unroll
        for (int i = 0; i < 16; ++i) { t1 += (double)r1[i]; t2 += (double)r2[i]; }
        double denom = (double)B_ * (double)F_;
        double tl  = t1 / denom;
        double ntl = t2 / denom;
        out[0] = (float)((1.0 - ALPHA_) * tl + ALPHA_ / (ntl + EPS_));
    }
}

// ---------- launch ----------
extern "C" void kernel_launch(void* const* d_in, const int* in_sizes, int n_in,
                              void* d_out, int out_size, void* d_ws, size_t ws_size,
                              hipStream_t stream) {
    const float* outputs  = (const float*)d_in[0];
    const float* clusters = (const float*)d_in[1];
    const int*   tgt      = (const int*)d_in[2];
    float* out = (float*)d_out;

    char* ws = (char*)d_ws;
    // workspace layout (16B-aligned), total 5,448,704 bytes
    u8*     At      = (u8*)(ws);                     // packed A: 2,097,152
    u8*     Bt      = (u8*)(ws + 2097152);           // packed B: 3,276,800
    float*  sumsq   = (float*)(ws + 5373952);        // 10496*4 = 41,984 (x2 | p2)
    u32*    swe     = (u32*)(ws + 5415936);          // 4096*4 (encoded wrong-class min)
    float*  stw     = (float*)(ws + 5432320);        // 4096*4 (target-class min)
    float*  x2      = sumsq;
    float*  p2      = sumsq + B_;

    init_kernel<<<(NROWS_ + B_ + 255) / 256, 256, 0, stream>>>(sumsq, swe);                 // 57 blocks
    prep_kernel<<<(B_ * 32 + N_ * 32) / 256, 256, 0, stream>>>(outputs, clusters, At, Bt, sumsq); // 1312
    score_kernel<<<dim3(N_ / BN, B_ / BM), 256, 0, stream>>>(At, Bt, p2, tgt, stw, swe);    // 50x32
    finalize_kernel<<<1, 1024, 0, stream>>>(stw, swe, x2, out);
}

// Round 10
// 113.827 us; speedup vs baseline: 1.1846x; 1.1846x over previous
//
#include <hip/hip_runtime.h>
#include <stdint.h>

// Problem constants (match reference)
#define B_ 4096
#define C_ 200
#define P_ 32
#define F_ 512
#define N_ (C_*P_)        // 6400 prototypes total
#define ALPHA_ 5.0
#define EPS_ 1e-8
#define NROWS_ (B_ + N_)  // 10496 sumsq rows (x2 then p2)

typedef unsigned char u8;
typedef __attribute__((ext_vector_type(4))) float floatx4;  // MFMA C/D frag

union frag16 { int4 v; long l[2]; };   // 16 fp8 = two MFMA k-slices (virtual-K)

__global__ void zero_kernel(float* __restrict__ sumsq) {
    int i = blockIdx.x * 256 + threadIdx.x;
    if (i < NROWS_) sumsq[i] = 0.f;
}

// ---------- prep: fp32 -> fp8 e4m3 packed + row sum-of-squares (x2 | p2) ----------
// Packed layout: o = tm*512 + kc*64 + q*16 + r (16-B units); byte (tm*8+kc)*1024 +
// (q*16+r)*16 holds features [kc*64+q*16,+16) of row tm*16+r. Output-indexed: writes
// wave-contiguous 1KB, reads per-lane 64B-aligned. One wave = one (tm,kc); lanes with
// equal r (q=0..3 at lane r+16q) reduce to a row-chunk sumsq, atomically accumulated.
__global__ void prep_kernel(const float* __restrict__ outputs, const float* __restrict__ clusters,
                            u8* __restrict__ At, u8* __restrict__ Bt, float* __restrict__ sumsq) {
    int t = blockIdx.x * 256 + threadIdx.x;
    const float* src; u8* dst; int o, rbase;
    if (t < B_ * 32) { o = t;           src = outputs;  dst = At; rbase = 0; }
    else             { o = t - B_ * 32; src = clusters; dst = Bt; rbase = B_; }
    const int tm = o >> 9, kc = (o >> 6) & 7, q = (o >> 4) & 3, r = o & 15;
    const int row = tm * 16 + r;
    const float4* s = (const float4*)(src + (size_t)row * F_ + kc * 64 + q * 16);
    float4 v0 = s[0], v1 = s[1], v2 = s[2], v3 = s[3];
    int4 w;
    w.x = __builtin_amdgcn_cvt_pk_fp8_f32(v0.x, v0.y, 0, false);
    w.x = __builtin_amdgcn_cvt_pk_fp8_f32(v0.z, v0.w, w.x, true);
    w.y = __builtin_amdgcn_cvt_pk_fp8_f32(v1.x, v1.y, 0, false);
    w.y = __builtin_amdgcn_cvt_pk_fp8_f32(v1.z, v1.w, w.y, true);
    w.z = __builtin_amdgcn_cvt_pk_fp8_f32(v2.x, v2.y, 0, false);
    w.z = __builtin_amdgcn_cvt_pk_fp8_f32(v2.z, v2.w, w.z, true);
    w.w = __builtin_amdgcn_cvt_pk_fp8_f32(v3.x, v3.y, 0, false);
    w.w = __builtin_amdgcn_cvt_pk_fp8_f32(v3.z, v3.w, w.w, true);
    *(int4*)(dst + (size_t)o * 16) = w;

    float ss = v0.x*v0.x + v0.y*v0.y + v0.z*v0.z + v0.w*v0.w
             + v1.x*v1.x + v1.y*v1.y + v1.z*v1.z + v1.w*v1.w
             + v2.x*v2.x + v2.y*v2.y + v2.z*v2.z + v2.w*v2.w
             + v3.x*v3.x + v3.y*v3.y + v3.z*v3.z + v3.w*v3.w;
    ss += __shfl_xor(ss, 16);
    ss += __shfl_xor(ss, 32);
    if ((o & 63) < 16) atomicAdd(&sumsq[rbase + row], ss);   // 16 lanes, 16 consecutive rows
}

// ---------- score kernel: fp8 MFMA GEMM, G->VGPR->LDS staged pipeline ----------
// Key structural change vs global_load_lds: in-flight global loads target PRIVATE
// registers, so __syncthreads needs only lgkmcnt(0) — prefetch loads issued for stage
// kc+2 stay in flight across the barrier. The ds_write of stage kc+1's registers waits
// only on loads issued a full stage earlier (already landed). No vmcnt(0) drain/stage.
#define BM 128
#define BN 128

__global__ __launch_bounds__(256, 4)
void score_kernel(const u8* __restrict__ At, const u8* __restrict__ Bt,
                  const float* __restrict__ p2, float* __restrict__ min_d) {
    __shared__ __align__(16) u8 lds[2][16384];   // [buf][ A: 8 tiles x 1KB | B: 8 tiles x 1KB ]

    const int tid  = threadIdx.x;
    const int lane = tid & 63;
    const int w    = tid >> 6;          // wave 0..3 (2x2 wave grid, 64x64 per wave)
    const int wm   = w >> 1, wn = w & 1;
    const int bx   = blockIdx.x;        // n-tile 0..49
    const int by   = blockIdx.y;        // m-tile 0..31
    const int m0   = by * BM, n0 = bx * BN;
    const int mrow = lane & 15;
    const int quad = lane >> 4;
    const int l16  = lane * 16;

    const u8* ag = At + ((size_t)(by * 8) << 13) + l16;   // 8 row-tiles x 8KB each
    const u8* bg = Bt + ((size_t)(bx * 8) << 13) + l16;
    // wave w stages A tiles {w, w+4} and B tiles {w, w+4}
    u8* wa0 = (u8*)lds[0] + w * 1024 + l16;               // stage-write bases (buf 0)
    const int woff1 = 16384;                              // buf1 - buf0

    floatx4 zf = {0.f, 0.f, 0.f, 0.f};
    floatx4 acc[4][4];
#pragma unroll
    for (int i = 0; i < 4; ++i)
#pragma unroll
        for (int j = 0; j < 4; ++j) acc[i][j] = zf;

    int4 rga0, rga1, rgb0, rgb1;   // staging registers (one stage: 4 x 16B per lane)
    #define GLOAD(k)  do {                                        \
        rga0 = *(const int4*)(ag + ((w * 8 + (k)) << 10));        \
        rga1 = *(const int4*)(ag + (((w + 4) * 8 + (k)) << 10));  \
        rgb0 = *(const int4*)(bg + ((w * 8 + (k)) << 10));        \
        rgb1 = *(const int4*)(bg + (((w + 4) * 8 + (k)) << 10));  \
    } while (0)
    #define LWRITE(buf) do {                                      \
        int d = (buf) * woff1;                                    \
        *(int4*)(wa0 + d)                = rga0;                  \
        *(int4*)(wa0 + d + 4096)         = rga1;                  \
        *(int4*)(wa0 + d + 8192)         = rgb0;                  \
        *(int4*)(wa0 + d + 12288)        = rgb1;                  \
    } while (0)

    // prologue: stage 0 -> lds[0]; stage 1 loads left in flight
    GLOAD(0);
    LWRITE(0);          // compiler inserts the vmcnt wait for the 4 loads here
    GLOAD(1);
    __syncthreads();    // lgkm drain only (ds_writes); stage-1 loads stay in flight

#pragma unroll
    for (int kc = 0; kc < 8; ++kc) {
        const int cur = kc & 1;
        frag16 a[4], b[4];
#pragma unroll
        for (int t = 0; t < 4; ++t) {
            a[t].v = *(const int4*)(lds[cur] + (wm * 4 + t) * 1024 + l16);
            b[t].v = *(const int4*)(lds[cur] + 8192 + (wn * 4 + t) * 1024 + l16);
        }
#pragma unroll
        for (int s = 0; s < 2; ++s)
#pragma unroll
            for (int mt = 0; mt < 4; ++mt)
#pragma unroll
                for (int nt = 0; nt < 4; ++nt)
                    acc[mt][nt] = __builtin_amdgcn_mfma_f32_16x16x32_fp8_fp8(
                        a[mt].l[s], b[nt].l[s], acc[mt][nt], 0, 0, 0);
        if (kc < 7) {
            LWRITE(cur ^ 1);          // regs for kc+1 (loaded a full stage ago)
            if (kc < 6) GLOAD(kc + 2);
        }
        __syncthreads();
    }
    #undef GLOAD
    #undef LWRITE

    // Epilogue: score = p2[n] - 2*xp (x2 constant per row b — argmins unchanged).
    // Only the min VALUE per class is needed. C/D layout: col = lane&15, row = quad*4+reg.
    float pg[4];
#pragma unroll
    for (int nt = 0; nt < 4; ++nt) pg[nt] = p2[n0 + wn * 64 + nt * 16 + mrow];

#pragma unroll
    for (int ch = 0; ch < 2; ++ch) {
        const int cls = bx * 4 + wn * 2 + ch;
#pragma unroll
        for (int mt = 0; mt < 4; ++mt)
#pragma unroll
            for (int reg = 0; reg < 4; ++reg) {
                float v = fminf(pg[ch * 2]     - 2.0f * acc[mt][ch * 2][reg],
                                pg[ch * 2 + 1] - 2.0f * acc[mt][ch * 2 + 1][reg]);
#pragma unroll
                for (int m = 8; m >= 1; m >>= 1) v = fminf(v, __shfl_xor(v, m));
                if (mrow == 0) {
                    int grow = m0 + wm * 64 + mt * 16 + quad * 4 + reg;
                    min_d[grow * C_ + cls] = v;
                }
            }
    }
}

// ---------- per-sample: target value + masked min over wrong classes (values only) ----------
__global__ void select_kernel(const float* __restrict__ min_d, const float* __restrict__ x2,
                              const int* __restrict__ tgt,
                              float* __restrict__ stw, float* __restrict__ sww) {
    int b    = blockIdx.x * 4 + (threadIdx.x >> 6);
    int lane = threadIdx.x & 63;
    int tc   = tgt[b];
    const float* row = min_d + (size_t)b * C_;

    float vt = row[tc];          // broadcast load
    float bw = 3.4e38f;
    for (int c = lane; c < C_; c += 64) {
        float v = row[c];
        if (c != tc) bw = fminf(bw, v);
    }
#pragma unroll
    for (int m = 32; m >= 1; m >>= 1) bw = fminf(bw, __shfl_xor(bw, m));
    if (lane == 0) {
        float xx = x2[b];
        stw[b] = xx + vt;        // = ||x - p_target*||^2 (fp8-dot approx)
        sww[b] = xx + bw;        // = ||x - p_wrong*||^2
    }
}

// Single-block reduction of 2x4096 floats + final loss
__global__ __launch_bounds__(1024)
void finalize_kernel(const float* __restrict__ stw, const float* __restrict__ sww,
                     float* __restrict__ out) {
    __shared__ float r1[16], r2[16];
    int tid = threadIdx.x;
    float s1 = 0.f, s2 = 0.f;
#pragma unroll
    for (int i = 0; i < 4; ++i) {
        s1 += stw[tid + i * 1024];
        s2 += sww[tid + i * 1024];
    }
#pragma unroll
    for (int m = 32; m >= 1; m >>= 1) { s1 += __shfl_xor(s1, m); s2 += __shfl_xor(s2, m); }
    if ((tid & 63) == 0) { r1[tid >> 6] = s1; r2[tid >> 6] = s2; }
    __syncthreads();
    if (tid == 0) {
        double t1 = 0.0, t2 = 0.0;
#pragma unroll
        for (int i = 0; i < 16; ++i) { t1 += (double)r1[i]; t2 += (double)r2[i]; }
        double denom = (double)B_ * (double)F_;
        double tl  = t1 / denom;
        double ntl = t2 / denom;
        out[0] = (float)((1.0 - ALPHA_) * tl + ALPHA_ / (ntl + EPS_));
    }
}

// ---------- launch ----------
extern "C" void kernel_launch(void* const* d_in, const int* in_sizes, int n_in,
                              void* d_out, int out_size, void* d_ws, size_t ws_size,
                              hipStream_t stream) {
    const float* outputs  = (const float*)d_in[0];
    const float* clusters = (const float*)d_in[1];
    const int*   tgt      = (const int*)d_in[2];
    float* out = (float*)d_out;

    char* ws = (char*)d_ws;
    // workspace layout (16B-aligned), total 8,692,736 bytes
    u8*     At      = (u8*)(ws);                     // packed A: 2,097,152
    u8*     Bt      = (u8*)(ws + 2097152);           // packed B: 3,276,800
    float*  sumsq   = (float*)(ws + 5373952);        // 10496*4 = 41,984 (x2 | p2)
    float*  min_d   = (float*)(ws + 5415936);        // 4096*200*4 = 3,276,800
    float*  x2      = sumsq;
    float*  p2      = sumsq + B_;
    // per-sample partials: reuse the At region (dead after score_kernel)
    float*  stw     = (float*)(ws);                  // 4096*4
    float*  sww     = (float*)(ws + 16384);          // 4096*4

    zero_kernel<<<(NROWS_ + 255) / 256, 256, 0, stream>>>(sumsq);                           // 41 blocks
    prep_kernel<<<(B_ * 32 + N_ * 32) / 256, 256, 0, stream>>>(outputs, clusters, At, Bt, sumsq); // 1312
    score_kernel<<<dim3(N_ / BN, B_ / BM), 256, 0, stream>>>(At, Bt, p2, min_d);            // 50x32
    select_kernel<<<B_ / 4, 256, 0, stream>>>(min_d, x2, tgt, stw, sww);                    // 1024
    finalize_kernel<<<1, 1024, 0, stream>>>(stw, sww, out);
}